// Round 9
// baseline (632.215 us; speedup 1.0000x reference)
//
#include <hip/hip_runtime.h>
#include <hip/hip_fp16.h>
#include <hip/hip_cooperative_groups.h>

namespace cg = cooperative_groups;

#define NN 50000      // nodes (fits in 16 bits: col packed as ushort)
#define NE 800000     // edges
#define DF 64         // features
#define MM 11         // (a,b) tuples
#define OUT_K 4       // DEPTH+1 output planes
#define PAD 16        // row slabs padded to multiple of PAD
#define SLAB_CAP (NE + (PAD - 1) * NN + 64)

__device__ __forceinline__ float bf2f(unsigned short u) {
    union { unsigned int i; float f; } v; v.i = ((unsigned int)u) << 16; return v.f;
}
__device__ __forceinline__ unsigned short f2bf(float f) {
    union { float f; unsigned int i; } v; v.f = f;
    unsigned int u = v.i + 0x7FFFu + ((v.i >> 16) & 1u);
    return (unsigned short)(u >> 16);
}

// SpMM row body: PAD-wide batches, no tail (slabs padded; pad recs are col=0,val=0)
__device__ __forceinline__ float spmm_row(const unsigned int* __restrict__ ecv,
                                          int s, int n,
                                          const unsigned short* __restrict__ xin,
                                          int lane) {
    float acc = 0.f;
    for (int i = s; i < s + n; i += PAD) {
        unsigned int rec[PAD];
        #pragma unroll
        for (int j = 0; j < PAD; ++j) rec[j] = __builtin_nontemporal_load(&ecv[i + j]);
        unsigned short g[PAD];
        float vv[PAD];
        #pragma unroll
        for (int j = 0; j < PAD; ++j) {
            int c = (int)(rec[j] & 0xFFFFu);
            vv[j] = __half2float(__ushort_as_half((unsigned short)(rec[j] >> 16)));
            g[j] = xin[c * DF + lane];
        }
        #pragma unroll
        for (int j = 0; j < PAD; ++j) acc += vv[j] * bf2f(g[j]);
    }
    return acc;
}

__global__ __launch_bounds__(256, 4) void k_mega(
    const int* __restrict__ row, const int* __restrict__ col,
    const float* __restrict__ ea, const float* __restrict__ alphas,
    const float* __restrict__ w, const float* __restrict__ a_arr,
    const float* __restrict__ b_arr, const float* __restrict__ x,
    int* __restrict__ deg, int* __restrict__ counter, int* __restrict__ fill,
    int* __restrict__ rowstart, float* __restrict__ dinv,
    unsigned int* __restrict__ ecv,
    unsigned short* __restrict__ xb0, unsigned short* __restrict__ xb1,
    unsigned short* __restrict__ xb2,
    float* __restrict__ y1, float* __restrict__ y2, float* __restrict__ gamma,
    float* __restrict__ out) {
    cg::grid_group grid = cg::this_grid();
    const int tid = blockIdx.x * blockDim.x + threadIdx.x;
    const int nth = gridDim.x * blockDim.x;
    const int lane = threadIdx.x & 63;
    const int wid = tid >> 6;
    const int nw = nth >> 6;

    // ---- P1: degree count ----
    for (int e = tid; e < NE; e += nth) atomicAdd(&deg[row[e]], 1);
    grid.sync();

    // ---- P2: slab alloc (padded, wave scan + 1 atomic/wave) + dinv + gamma ----
    for (int i0 = wid * 64; i0 < NN; i0 += nw * 64) {
        int i = i0 + lane;
        int d = (i < NN) ? deg[i] : 0;
        int dp = (d + PAD - 1) & ~(PAD - 1);
        int v = dp;
        #pragma unroll
        for (int off = 1; off < 64; off <<= 1) {
            int t = __shfl_up(v, off, 64);
            if (lane >= off) v += t;
        }
        int total = __shfl(v, 63, 64);
        int base = 0;
        if (lane == 63) base = atomicAdd(counter, total);
        base = __shfl(base, 63, 64);
        if (i < NN) {
            rowstart[i] = base + v - dp;
            dinv[i] = 1.0f / sqrtf((float)(d == 0 ? 1 : d));
        }
    }
    // gamma[k][j] = sum_m w_m c_{k,m,j}; fully unrolled -> registers only
    if (tid == 0) {
        float g[OUT_K][OUT_K];
        #pragma unroll
        for (int k = 0; k < OUT_K; ++k)
            #pragma unroll
            for (int j = 0; j < OUT_K; ++j) g[k][j] = 0.f;
        for (int m = 0; m < MM; ++m) {
            float a = a_arr[m], b = b_arr[m], wm = w[m];
            float c0[OUT_K], c1v[OUT_K], c2v[OUT_K], c3v[OUT_K];
            #pragma unroll
            for (int j = 0; j < OUT_K; ++j) { c0[j] = 0.f; c1v[j] = 0.f; c2v[j] = 0.f; c3v[j] = 0.f; }
            c0[0] = 1.f;
            float al0 = alphas[m];
            c1v[0] = al0 * 0.5f * (a - b);
            c1v[1] = al0 * 0.5f * (a + b + 2.f);
            #pragma unroll
            for (int L = 2; L <= 3; ++L) {
                float Lf = (float)L;
                float alL = alphas[(L - 1) * MM + m];
                float alm = alphas[(L - 2) * MM + m];
                float ab = a + b;
                float t2L = 2.f * Lf + ab;
                float coef_l = 2.f * Lf * (Lf + ab) * (t2L - 2.f);
                float inv = 1.f / coef_l;
                float t1 = alL * ((t2L - 1.f) * t2L * (t2L - 2.f)) * inv;
                float t2 = alL * ((t2L - 1.f) * (a * a - b * b)) * inv;
                float t3 = alL * alm * (2.f * (Lf - 1.f + a) * (Lf - 1.f + b) * t2L) * inv;
                #pragma unroll
                for (int j = OUT_K - 1; j >= 0; --j) {
                    float ps, pc, pp;
                    if (L == 2) { ps = (j > 0) ? c1v[j - 1] : 0.f; pc = c1v[j]; pp = c0[j]; }
                    else        { ps = (j > 0) ? c2v[j - 1] : 0.f; pc = c2v[j]; pp = c1v[j]; }
                    float nv = t1 * ps - t2 * pc - t3 * pp;
                    if (L == 2) c2v[j] = nv; else c3v[j] = nv;
                }
            }
            #pragma unroll
            for (int j = 0; j < OUT_K; ++j) {
                g[0][j] += wm * c0[j];
                g[1][j] += wm * c1v[j];
                g[2][j] += wm * c2v[j];
                g[3][j] += wm * c3v[j];
            }
        }
        #pragma unroll
        for (int k = 0; k < OUT_K; ++k)
            #pragma unroll
            for (int j = 0; j < OUT_K; ++j) gamma[k * OUT_K + j] = g[k][j];
    }
    grid.sync();

    // ---- P3: fill edge records (low16=col, high16=fp16 val) + bf16 cast of x ----
    for (int e = tid; e < NE; e += nth) {
        int r = row[e], c = col[e];
        int pos = rowstart[r] + atomicAdd(&fill[r], 1);
        float v = dinv[r] * ea[e] * dinv[c];
        unsigned short hb = __half_as_ushort(__float2half(v));
        ecv[pos] = (unsigned int)(unsigned short)c | ((unsigned int)hb << 16);
    }
    for (int i = tid; i < NN * DF; i += nth) xb0[i] = f2bf(x[i]);
    grid.sync();

    // ---- P4: y1 = S x ----
    for (int r = wid; r < NN; r += nw) {
        int s = rowstart[r];
        int n = (deg[r] + PAD - 1) & ~(PAD - 1);
        float acc = spmm_row(ecv, s, n, xb0, lane);
        y1[r * DF + lane] = acc;
        xb1[r * DF + lane] = f2bf(acc);
    }
    grid.sync();

    // ---- P5: y2 = S y1 ----
    for (int r = wid; r < NN; r += nw) {
        int s = rowstart[r];
        int n = (deg[r] + PAD - 1) & ~(PAD - 1);
        float acc = spmm_row(ecv, s, n, xb1, lane);
        y2[r * DF + lane] = acc;
        xb2[r * DF + lane] = f2bf(acc);
    }
    grid.sync();

    // ---- P6: y3 = S y2 fused with combine ----
    float gm[OUT_K * OUT_K];
    #pragma unroll
    for (int t = 0; t < OUT_K * OUT_K; ++t) gm[t] = gamma[t];
    for (int r = wid; r < NN; r += nw) {
        int s = rowstart[r];
        int n = (deg[r] + PAD - 1) & ~(PAD - 1);
        float v3 = spmm_row(ecv, s, n, xb2, lane);
        int i = r * DF + lane;
        float v0 = x[i], v1 = y1[i], v2 = y2[i];
        #pragma unroll
        for (int k = 0; k < OUT_K; ++k) {
            float o = gm[k * OUT_K + 0] * v0 + gm[k * OUT_K + 1] * v1 +
                      gm[k * OUT_K + 2] * v2 + gm[k * OUT_K + 3] * v3;
            out[(r * OUT_K + k) * DF + lane] = o;
        }
    }
}

// ---------------- launch ----------------

extern "C" void kernel_launch(void* const* d_in, const int* in_sizes, int n_in,
                              void* d_out, int out_size, void* d_ws, size_t ws_size,
                              hipStream_t stream) {
    const float* x      = (const float*)d_in[0];
    const int*   ei     = (const int*)d_in[1];
    const float* ea     = (const float*)d_in[2];
    const float* alphas = (const float*)d_in[3];
    const float* w      = (const float*)d_in[4];
    const float* a_arr  = (const float*)d_in[5];
    const float* b_arr  = (const float*)d_in[6];
    float* out = (float*)d_out;
    const int* row = ei;
    const int* col = ei + NE;

    char* ws = (char*)d_ws;
    size_t off = 0;
    auto alloc = [&](size_t bytes) {
        void* p = ws + off;
        off = (off + bytes + 255) & ~(size_t)255;
        return p;
    };
    // deg/fill/counter then ecv contiguous: ONE memset zeroes all (pad recs must be 0)
    int* deg      = (int*)alloc((size_t)(2 * NN + 1) * sizeof(int));
    int* fill     = deg + NN;
    int* counter  = deg + 2 * NN;
    unsigned int* ecv = (unsigned int*)alloc((size_t)SLAB_CAP * sizeof(unsigned int));
    size_t zero_end = off;
    int* rowstart = (int*)alloc((size_t)NN * sizeof(int));
    float* dinv   = (float*)alloc((size_t)NN * sizeof(float));
    unsigned short* xb0 = (unsigned short*)alloc((size_t)NN * DF * sizeof(unsigned short));
    unsigned short* xb1 = (unsigned short*)alloc((size_t)NN * DF * sizeof(unsigned short));
    unsigned short* xb2 = (unsigned short*)alloc((size_t)NN * DF * sizeof(unsigned short));
    float* y1 = (float*)alloc((size_t)NN * DF * sizeof(float));
    float* y2 = (float*)alloc((size_t)NN * DF * sizeof(float));
    float* gamma = (float*)alloc((size_t)OUT_K * OUT_K * sizeof(float));

    (void)hipMemsetAsync(deg, 0, zero_end, stream);

    int maxBlocksPerCU = 0;
    (void)hipOccupancyMaxActiveBlocksPerMultiprocessor(&maxBlocksPerCU, k_mega, 256, 0);
    if (maxBlocksPerCU < 1) maxBlocksPerCU = 1;
    int gridBlocks = maxBlocksPerCU * 256;   // 256 CUs
    if (gridBlocks > 1024) gridBlocks = 1024;

    void* args[] = {
        (void*)&row, (void*)&col, (void*)&ea, (void*)&alphas, (void*)&w,
        (void*)&a_arr, (void*)&b_arr, (void*)&x,
        (void*)&deg, (void*)&counter, (void*)&fill, (void*)&rowstart, (void*)&dinv,
        (void*)&ecv, (void*)&xb0, (void*)&xb1, (void*)&xb2,
        (void*)&y1, (void*)&y2, (void*)&gamma, (void*)&out
    };
    (void)hipLaunchCooperativeKernel((void*)k_mega, dim3(gridBlocks), dim3(256),
                                     args, 0, stream);
}